// Round 6
// baseline (427.712 us; speedup 1.0000x reference)
//
#include <hip/hip_runtime.h>
#include <stdint.h>
#include <stddef.h>

typedef __attribute__((ext_vector_type(8))) short short8;
typedef __attribute__((ext_vector_type(4))) float f32x4;

#define T_DIM 8192
#define M_DIM 4096
#define K_DIM 4096

// f32 -> bf16 round-to-nearest-even
__device__ __forceinline__ unsigned short f2b(float f) {
    unsigned int u = __builtin_bit_cast(unsigned int, f);
    u += 0x7fffu + ((u >> 16) & 1u);
    return (unsigned short)(u >> 16);
}

__device__ __forceinline__ void async_copy16(const void* g, const void* l) {
    __builtin_amdgcn_global_load_lds(
        (const __attribute__((address_space(1))) unsigned int*)g,
        (__attribute__((address_space(3))) unsigned int*)l,
        16, 0, 0);
}

// ---------------------------------------------------------------------------
// Fused prep: blocks [0,8192) dequant w -> qw(f32) + qwb(bf16);
//             blocks [8192,24576) convert x -> xb(bf16).
// ---------------------------------------------------------------------------
__global__ void prep_kernel(const float* __restrict__ w,
                            const float* __restrict__ maxval,
                            const float* __restrict__ lut_g,
                            float* __restrict__ qw,
                            unsigned short* __restrict__ qwb,
                            const float* __restrict__ x,
                            unsigned short* __restrict__ xb) {
    __shared__ float lut[16];
    const int bid = blockIdx.x;
    if (bid < 8192) {
        if (threadIdx.x < 16) lut[threadIdx.x] = lut_g[threadIdx.x];
        __syncthreads();

        size_t base = ((size_t)bid * 256 + threadIdx.x) * 8;
        float mv = maxval[base >> 6];

        float4 w0 = *reinterpret_cast<const float4*>(w + base);
        float4 w1 = *reinterpret_cast<const float4*>(w + base + 4);
        float vin[8] = {w0.x, w0.y, w0.z, w0.w, w1.x, w1.y, w1.z, w1.w};
        float outv[8];

        #pragma unroll
        for (int e = 0; e < 8; ++e) {
            float v = vin[e] / mv;
            float bd = fabsf(v - lut[0]);
            int best = 0;
            #pragma unroll
            for (int k = 1; k < 16; ++k) {
                float d = fabsf(v - lut[k]);
                if (d < bd) { bd = d; best = k; }
            }
            outv[e] = lut[best] * mv;
        }

        float4 o0; o0.x = outv[0]; o0.y = outv[1]; o0.z = outv[2]; o0.w = outv[3];
        float4 o1; o1.x = outv[4]; o1.y = outv[5]; o1.z = outv[6]; o1.w = outv[7];
        *reinterpret_cast<float4*>(qw + base)     = o0;
        *reinterpret_cast<float4*>(qw + base + 4) = o1;

        if (qwb != nullptr) {
            short8 pk;
            #pragma unroll
            for (int e = 0; e < 8; ++e) pk[e] = (short)f2b(outv[e]);
            *reinterpret_cast<short8*>(qwb + base) = pk;
        }
    } else {
        size_t base = ((size_t)(bid - 8192) * 256 + threadIdx.x) * 8;
        float4 a = *reinterpret_cast<const float4*>(x + base);
        float4 b = *reinterpret_cast<const float4*>(x + base + 4);
        short8 pk;
        pk[0] = (short)f2b(a.x); pk[1] = (short)f2b(a.y);
        pk[2] = (short)f2b(a.z); pk[3] = (short)f2b(a.w);
        pk[4] = (short)f2b(b.x); pk[5] = (short)f2b(b.y);
        pk[6] = (short)f2b(b.z); pk[7] = (short)f2b(b.w);
        *reinterpret_cast<short8*>(xb + base) = pk;
    }
}

// ---------------------------------------------------------------------------
// 256x256 8-phase GEMM, 16x16x32 MFMA, pipelined fragment reads:
//   Y[t][m] = sum_k A[t][k]*B[m][k]
// 8 waves (2Mx4N), BK=64, 128 KiB LDS dbuf.
// Regions per buffer (16 KiB each):
//   r0 = A rows (r%128)<64   (MH0)   r1 = B rows (r%64)>=32 (NH1)
//   r2 = A rows (r%128)>=64  (MH1)   r3 = B rows (r%64)<32  (NH0)
// Snake quads: P0=(0,0) P1=(0,1) P2=(1,1) P3=(1,0).
// Fragment reads are issued ONE PHASE BEFORE use (never waited on in-phase):
//   P0 reads B1 (for P1); P1 reads A1 (for P2/P3); P2 none;
//   P3: stage, vmcnt(6)+barrier (in-order retirement => tile t+1 complete),
//       then reads NEXT tile's A0/B0 into the alternate reg set, then MFMA.
// A0/B0 reg sets (a/b) ping-pong per half-iteration (static names, rule #20).
// Staging: region r of tile t+2 issued at tile t phase r+1 (r3(t+1) at P0(t)).
// 16-row-band reads + 3-bit XOR swizzle = 0 bank conflicts (R3/R5 PMC);
// do NOT widen to 32-row bands (R4: 2.5e7 conflicts).
// ---------------------------------------------------------------------------

#define RD_A0(BUF, DST)                                                       \
  { _Pragma("unroll") for (int mi = 0; mi < 4; ++mi) {                        \
      _Pragma("unroll") for (int k2 = 0; k2 < 2; ++k2) {                      \
        int lr = wr * 64 + mi * 16 + fr;                                      \
        DST[mi][k2] = *reinterpret_cast<const short8*>(                       \
            lds + (BUF) * 65536 + lr * 128 +                                  \
            ((k2 * 64 + fkB) ^ ((lr & 7) << 4)));                             \
  } } }

#define RD_A1(BUF)                                                            \
  { _Pragma("unroll") for (int mi = 0; mi < 4; ++mi) {                        \
      _Pragma("unroll") for (int k2 = 0; k2 < 2; ++k2) {                      \
        int lr = wr * 64 + mi * 16 + fr;                                      \
        aR1[mi][k2] = *reinterpret_cast<const short8*>(                       \
            lds + (BUF) * 65536 + 32768 + lr * 128 +                          \
            ((k2 * 64 + fkB) ^ ((lr & 7) << 4)));                             \
  } } }

#define RD_Bx(BUF, OFF, DST)                                                  \
  { _Pragma("unroll") for (int ni = 0; ni < 2; ++ni) {                        \
      _Pragma("unroll") for (int k2 = 0; k2 < 2; ++k2) {                      \
        int lr = wc * 32 + ni * 16 + fr;                                      \
        DST[ni][k2] = *reinterpret_cast<const short8*>(                       \
            lds + (BUF) * 65536 + (OFF) + lr * 128 +                          \
            ((k2 * 64 + fkB) ^ ((lr & 7) << 4)));                             \
  } } }

#define MFMA_Q(MH, NH, A, B)                                                  \
    _Pragma("unroll") for (int mi = 0; mi < 4; ++mi)                          \
    _Pragma("unroll") for (int ni = 0; ni < 2; ++ni)                          \
    _Pragma("unroll") for (int k2 = 0; k2 < 2; ++k2)                          \
      acc[(MH) * 4 + mi][(NH) * 2 + ni] =                                     \
          __builtin_amdgcn_mfma_f32_16x16x32_bf16(                            \
              A[mi][k2], B[ni][k2],                                           \
              acc[(MH) * 4 + mi][(NH) * 2 + ni], 0, 0, 0);

#define PH_P0(BUF, ACUR, B0CUR)                                               \
  { RD_Bx(BUF, 16384, bR1)                                                    \
    issue_seq(seq); ++seq;                                                    \
    asm volatile("" ::: "memory");                                            \
    __builtin_amdgcn_s_barrier();                                             \
    __builtin_amdgcn_s_setprio(1);                                            \
    MFMA_Q(0, 0, ACUR, B0CUR)                                                 \
    __builtin_amdgcn_s_setprio(0);                                            \
    asm volatile("" ::: "memory");                                            \
    __builtin_amdgcn_s_barrier(); }

#define PH_P1(BUF, ACUR)                                                      \
  { RD_A1(BUF)                                                                \
    issue_seq(seq); ++seq;                                                    \
    asm volatile("" ::: "memory");                                            \
    __builtin_amdgcn_s_barrier();                                             \
    __builtin_amdgcn_s_setprio(1);                                            \
    MFMA_Q(0, 1, ACUR, bR1)                                                   \
    __builtin_amdgcn_s_setprio(0);                                            \
    asm volatile("" ::: "memory");                                            \
    __builtin_amdgcn_s_barrier(); }

#define PH_P2(BUF)                                                            \
  { issue_seq(seq); ++seq;                                                    \
    asm volatile("" ::: "memory");                                            \
    __builtin_amdgcn_s_barrier();                                             \
    __builtin_amdgcn_s_setprio(1);                                            \
    MFMA_Q(1, 1, aR1, bR1)                                                    \
    __builtin_amdgcn_s_setprio(0);                                            \
    asm volatile("" ::: "memory");                                            \
    __builtin_amdgcn_s_barrier(); }

// P3: stage, vmcnt(6)+barrier (tile t+1 now complete), pre-read next tile's
// A0/B0 into the alternate set, MFMA(1,0) hides the read latency.
#define PH_P3(BUF, B0CUR, ANXT, B0NXT)                                        \
  { issue_seq(seq); ++seq;                                                    \
    asm volatile("s_waitcnt vmcnt(6)" ::: "memory");                          \
    __builtin_amdgcn_s_barrier();                                             \
    RD_A0((BUF) ^ 1, ANXT)                                                    \
    RD_Bx((BUF) ^ 1, 49152, B0NXT)                                            \
    __builtin_amdgcn_s_setprio(1);                                            \
    MFMA_Q(1, 0, aR1, B0CUR)                                                  \
    __builtin_amdgcn_s_setprio(0);                                            \
    asm volatile("" ::: "memory");                                            \
    __builtin_amdgcn_s_barrier(); }

__global__ __launch_bounds__(512, 2) void gemm8p(
    const unsigned short* __restrict__ Abf,   // [T_DIM][K_DIM] bf16
    const unsigned short* __restrict__ Bbf,   // [M_DIM][K_DIM] bf16
    float* __restrict__ Y) {                  // [T_DIM][M_DIM]
    __shared__ __align__(16) unsigned char lds[131072];

    const int tid  = threadIdx.x;
    const int lane = tid & 63;
    const int wid  = tid >> 6;   // 0..7
    const int wr   = wid >> 2;   // 0..1 (M half of tile)
    const int wc   = wid & 3;    // 0..3 (N quarter of tile)

    // T1: bijective XCD swizzle (512 % 8 == 0)
    const int bid  = blockIdx.x;
    const int swz  = (bid & 7) * 64 + (bid >> 3);
    const int brow = swz >> 4;          // T/256 = 32
    const int bcol = swz & 15;          // M/256 = 16
    const int row0 = brow * 256;
    const int col0 = bcol * 256;

    const int fr  = lane & 15;
    const int fkB = (lane >> 4) * 16;   // byte offset of k-fragment

    f32x4 acc[8][4] = {};
    short8 aA_a[4][2], aA_b[4][2];      // A-MH0 sets (cross-tile pipelined)
    short8 bZ_a[2][2], bZ_b[2][2];      // B-NH0 sets (cross-tile pipelined)
    short8 aR1[4][2];                   // A-MH1 (within-tile)
    short8 bR1[2][2];                   // B-NH1 (within-tile)

    // staging: seq s -> K-tile s>>2, region s&3 (stage order r0,r1,r2,r3)
    auto issue_seq = [&](int s) {
        int t   = s >> 2;
        int idx = s & 3;
        int buf = t & 1;
        int tc  = t < 64 ? t : 63;          // clamp tail prefetch (dead data)
        unsigned regoff = buf * 65536u + idx * 16384u;
        #pragma unroll
        for (int j = 0; j < 2; ++j) {
            int lr = j * 64 + wid * 8 + (lane >> 3);   // region row 0..127
            const unsigned short* Mat;
            int grow;
            if (idx == 0)      { Mat = Abf; grow = row0 + ((lr >> 6) << 7) + (lr & 63); }
            else if (idx == 2) { Mat = Abf; grow = row0 + 64 + ((lr >> 6) << 7) + (lr & 63); }
            else if (idx == 1) { Mat = Bbf; grow = col0 + ((lr >> 5) << 6) + 32 + (lr & 31); }
            else               { Mat = Bbf; grow = col0 + ((lr >> 5) << 6) + (lr & 31); }
            int cb = ((lane & 7) * 16) ^ ((lr & 7) << 4);   // T2 pre-swizzled source
            const char* g = (const char*)(Mat + (size_t)grow * K_DIM + tc * 64) + cb;
            async_copy16(g, lds + regoff + j * 8192u + wid * 1024u);  // linear dest
        }
    };

    // prologue: tile0 (4 regions), vmcnt(4), tile1 regions 0-2, vmcnt(6),
    // then pre-read tile0's A0/B0 into set a.
    int seq = 0;
    issue_seq(seq); ++seq;
    issue_seq(seq); ++seq;
    issue_seq(seq); ++seq;
    issue_seq(seq); ++seq;
    asm volatile("s_waitcnt vmcnt(4)" ::: "memory");
    issue_seq(seq); ++seq;
    issue_seq(seq); ++seq;
    issue_seq(seq); ++seq;
    asm volatile("s_waitcnt vmcnt(6)" ::: "memory");   // tile0 fully landed
    __builtin_amdgcn_s_barrier();
    RD_A0(0, aA_a)
    RD_Bx(0, 49152, bZ_a)

    // main loop: 32 iterations x 2 K-tiles, 4 phases each (snake quad order)
    for (int i = 0; i < 32; ++i) {
        PH_P0(0, aA_a, bZ_a)
        PH_P1(0, aA_a)
        PH_P2(0)
        PH_P3(0, bZ_a, aA_b, bZ_b)   // pre-read tile(2i+1) from buf1 -> set b
        PH_P0(1, aA_b, bZ_b)
        PH_P1(1, aA_b)
        PH_P2(1)
        PH_P3(1, bZ_b, aA_a, bZ_a)   // pre-read tile(2i+2) from buf0 -> set a
    }
    asm volatile("s_waitcnt vmcnt(0)" ::: "memory");   // epilogue drain

    // epilogue: C/D layout col=lane&15, row=(lane>>4)*4+reg
    const int rb = (lane >> 4) * 4;
    #pragma unroll
    for (int m = 0; m < 8; ++m)
        #pragma unroll
        for (int n = 0; n < 4; ++n)
            #pragma unroll
            for (int r = 0; r < 4; ++r)
                Y[(size_t)(row0 + wr * 128 + m * 16 + rb + r) * M_DIM +
                  col0 + wc * 64 + n * 16 + fr] = acc[m][n][r];
}

// ---------------------------------------------------------------------------
// Fallback m97-style GEMM (only if ws_size too small for bf16 staging)
// ---------------------------------------------------------------------------
template <bool BF32>
__global__ __launch_bounds__(256) void gemm_kernel(const float* __restrict__ Ap,
                                                   const void* __restrict__ Bp,
                                                   float* __restrict__ Y) {
    constexpr int BK = 64;
    __shared__ unsigned short lA[128 * BK];
    __shared__ unsigned short lB[128 * BK];

    const int tid  = threadIdx.x;
    const int lane = tid & 63;
    const int wid  = tid >> 6;
    const int wr   = wid >> 1;
    const int wc   = wid & 1;
    const int brow = blockIdx.x >> 5;
    const int bcol = blockIdx.x & 31;
    const int row0 = brow * 128;
    const int col0 = bcol * 128;

    f32x4 acc[4][4] = {};

    const int fr = lane & 15;
    const int fk = (lane >> 4) * 8;
    const int srow = lane >> 3;
    const int scol = (lane & 7) * 8;

    for (int k0 = 0; k0 < K_DIM; k0 += BK) {
        #pragma unroll
        for (int i = 0; i < 4; ++i) {
            const int c = wid * 4 + i;
            const int r = c * 8 + srow;
            const float* g = Ap + (size_t)(row0 + r) * K_DIM + k0 + scol;
            float4 v0 = *reinterpret_cast<const float4*>(g);
            float4 v1 = *reinterpret_cast<const float4*>(g + 4);
            short8 pk;
            pk[0] = (short)f2b(v0.x); pk[1] = (short)f2b(v0.y);
            pk[2] = (short)f2b(v0.z); pk[3] = (short)f2b(v0.w);
            pk[4] = (short)f2b(v1.x); pk[5] = (short)f2b(v1.y);
            pk[6] = (short)f2b(v1.z); pk[7] = (short)f2b(v1.w);
            *reinterpret_cast<short8*>(lA + c * 512 + lane * 8) = pk;
        }
        #pragma unroll
        for (int i = 0; i < 4; ++i) {
            const int c = wid * 4 + i;
            const int r = c * 8 + srow;
            if constexpr (!BF32) {
                async_copy16((const unsigned short*)Bp + (size_t)(col0 + r) * K_DIM + k0 + scol,
                             lB + c * 512);
            } else {
                const float* g = (const float*)Bp + (size_t)(col0 + r) * K_DIM + k0 + scol;
                float4 v0 = *reinterpret_cast<const float4*>(g);
                float4 v1 = *reinterpret_cast<const float4*>(g + 4);
                short8 pk;
                pk[0] = (short)f2b(v0.x); pk[1] = (short)f2b(v0.y);
                pk[2] = (short)f2b(v0.z); pk[3] = (short)f2b(v0.w);
                pk[4] = (short)f2b(v1.x); pk[5] = (short)f2b(v1.y);
                pk[6] = (short)f2b(v1.z); pk[7] = (short)f2b(v1.w);
                *reinterpret_cast<short8*>(lB + c * 512 + lane * 8) = pk;
            }
        }
        __syncthreads();

        #pragma unroll
        for (int kk = 0; kk < BK; kk += 32) {
            short8 af[4], bfr[4];
            #pragma unroll
            for (int m = 0; m < 4; ++m)
                af[m] = *reinterpret_cast<const short8*>(
                    lA + (wr * 64 + m * 16 + fr) * BK + kk + fk);
            #pragma unroll
            for (int n = 0; n < 4; ++n)
                bfr[n] = *reinterpret_cast<const short8*>(
                    lB + (wc * 64 + n * 16 + fr) * BK + kk + fk);
            #pragma unroll
            for (int m = 0; m < 4; ++m)
                #pragma unroll
                for (int n = 0; n < 4; ++n)
                    acc[m][n] = __builtin_amdgcn_mfma_f32_16x16x32_bf16(
                        af[m], bfr[n], acc[m][n], 0, 0, 0);
        }
        __syncthreads();
    }

    const int orow  = row0 + wr * 64;
    const int ocol  = col0 + wc * 64 + fr;
    const int rbase = (lane >> 4) * 4;
    #pragma unroll
    for (int m = 0; m < 4; ++m)
        #pragma unroll
        for (int n = 0; n < 4; ++n)
            #pragma unroll
            for (int r = 0; r < 4; ++r)
                Y[(size_t)(orow + m * 16 + rbase + r) * M_DIM + ocol + n * 16] =
                    acc[m][n][r];
}

// ---------------------------------------------------------------------------
extern "C" void kernel_launch(void* const* d_in, const int* in_sizes, int n_in,
                              void* d_out, int out_size, void* d_ws, size_t ws_size,
                              hipStream_t stream) {
    const float* x   = (const float*)d_in[0];
    const float* w   = (const float*)d_in[1];
    const float* mv  = (const float*)d_in[2];
    const float* lut = (const float*)d_in[3];

    float* y  = (float*)d_out;
    float* qw = y + (size_t)T_DIM * M_DIM;

    const size_t nx = (size_t)T_DIM * K_DIM;
    const size_t nw = (size_t)M_DIM * K_DIM;

    unsigned short* wsu = (unsigned short*)d_ws;
    const bool full  = ws_size >= (nx + nw) * sizeof(unsigned short);   // 96 MB
    const bool bonly = !full && ws_size >= nw * sizeof(unsigned short); // 32 MB

    unsigned short* xb  = full ? wsu : nullptr;
    unsigned short* qwb = full ? (wsu + nx) : (bonly ? wsu : nullptr);

    unsigned prep_blocks = (unsigned)(nw / 2048) + (full ? (unsigned)(nx / 2048) : 0u);
    prep_kernel<<<dim3(prep_blocks), dim3(256), 0, stream>>>(
        w, mv, lut, qw, qwb, x, xb);

    if (full) {
        dim3 grid((T_DIM / 256) * (M_DIM / 256));   // 32*16 = 512
        gemm8p<<<grid, dim3(512), 0, stream>>>(xb, qwb, y);
    } else {
        dim3 grid((T_DIM / 128) * (M_DIM / 128));   // 2048
        dim3 blk(256);
        if (bonly)
            gemm_kernel<false><<<grid, blk, 0, stream>>>(x, qwb, y);
        else
            gemm_kernel<true><<<grid, blk, 0, stream>>>(x, qw, y);
    }
}

// Round 7
// 290.558 us; speedup vs baseline: 1.4720x; 1.4720x over previous
//
#include <hip/hip_runtime.h>
#include <stdint.h>
#include <stddef.h>

typedef __attribute__((ext_vector_type(8))) short short8;
typedef __attribute__((ext_vector_type(4))) float f32x4;

#define T_DIM 8192
#define M_DIM 4096
#define K_DIM 4096

// f32 -> bf16 round-to-nearest-even
__device__ __forceinline__ unsigned short f2b(float f) {
    unsigned int u = __builtin_bit_cast(unsigned int, f);
    u += 0x7fffu + ((u >> 16) & 1u);
    return (unsigned short)(u >> 16);
}

__device__ __forceinline__ void async_copy16(const void* g, const void* l) {
    __builtin_amdgcn_global_load_lds(
        (const __attribute__((address_space(1))) unsigned int*)g,
        (__attribute__((address_space(3))) unsigned int*)l,
        16, 0, 0);
}

// ---------------------------------------------------------------------------
// Fused prep: blocks [0,8192) dequant w -> qw(f32) + qwb(bf16);
//             blocks [8192,24576) convert x -> xb(bf16).
// ---------------------------------------------------------------------------
__global__ void prep_kernel(const float* __restrict__ w,
                            const float* __restrict__ maxval,
                            const float* __restrict__ lut_g,
                            float* __restrict__ qw,
                            unsigned short* __restrict__ qwb,
                            const float* __restrict__ x,
                            unsigned short* __restrict__ xb) {
    __shared__ float lut[16];
    const int bid = blockIdx.x;
    if (bid < 8192) {
        if (threadIdx.x < 16) lut[threadIdx.x] = lut_g[threadIdx.x];
        __syncthreads();

        size_t base = ((size_t)bid * 256 + threadIdx.x) * 8;
        float mv = maxval[base >> 6];

        float4 w0 = *reinterpret_cast<const float4*>(w + base);
        float4 w1 = *reinterpret_cast<const float4*>(w + base + 4);
        float vin[8] = {w0.x, w0.y, w0.z, w0.w, w1.x, w1.y, w1.z, w1.w};
        float outv[8];

        #pragma unroll
        for (int e = 0; e < 8; ++e) {
            float v = vin[e] / mv;
            float bd = fabsf(v - lut[0]);
            int best = 0;
            #pragma unroll
            for (int k = 1; k < 16; ++k) {
                float d = fabsf(v - lut[k]);
                if (d < bd) { bd = d; best = k; }
            }
            outv[e] = lut[best] * mv;
        }

        float4 o0; o0.x = outv[0]; o0.y = outv[1]; o0.z = outv[2]; o0.w = outv[3];
        float4 o1; o1.x = outv[4]; o1.y = outv[5]; o1.z = outv[6]; o1.w = outv[7];
        *reinterpret_cast<float4*>(qw + base)     = o0;
        *reinterpret_cast<float4*>(qw + base + 4) = o1;

        if (qwb != nullptr) {
            short8 pk;
            #pragma unroll
            for (int e = 0; e < 8; ++e) pk[e] = (short)f2b(outv[e]);
            *reinterpret_cast<short8*>(qwb + base) = pk;
        }
    } else {
        size_t base = ((size_t)(bid - 8192) * 256 + threadIdx.x) * 8;
        float4 a = *reinterpret_cast<const float4*>(x + base);
        float4 b = *reinterpret_cast<const float4*>(x + base + 4);
        short8 pk;
        pk[0] = (short)f2b(a.x); pk[1] = (short)f2b(a.y);
        pk[2] = (short)f2b(a.z); pk[3] = (short)f2b(a.w);
        pk[4] = (short)f2b(b.x); pk[5] = (short)f2b(b.y);
        pk[6] = (short)f2b(b.z); pk[7] = (short)f2b(b.w);
        *reinterpret_cast<short8*>(xb + base) = pk;
    }
}

// ---------------------------------------------------------------------------
// 256x256 GEMM, 16x16x32 MFMA, SINGLE barrier per phase:
//   Y[t][m] = sum_k A[t][k]*B[m][k]
// 8 waves (2Mx4N), BK=64, 128 KiB LDS dbuf.
// Regions per buffer (16 KiB each):
//   r0 = A rows (r%128)<64   (MH0)   r1 = B rows (r%64)>=32 (NH1)
//   r2 = A rows (r%128)>=64  (MH1)   r3 = B rows (r%64)<32  (NH0)
// Snake quads: P0=(0,0) P1=(0,1) P2=(1,1) P3=(1,0).
// bR0 read once at P0, reused at P3 (24 ds_read_b128/K-tile/wave: 12/4/8/0).
// Phase = { reads_p; stage_p; fence; barrier; fence; MFMA_p } — NO post-MFMA
// barrier. Safety: stage at phase p+1 writes the region last-read at phase p;
// every wave issued its reads_p before barrier_p, and any wave can issue
// stage_{p+1} only after passing barrier_p. The staged region is never the
// concurrently-read region (P1 writes r0, reads r1; P2 writes r1, reads r2;
// P3 writes r2, reads none; P0 writes r3 of the OTHER buffer).
// vmcnt(6) at end of P3 (memory-fenced) gates next tile's reads per-wave.
// Fence-free window MFMA_p -> reads_{p+1} lets the compiler overlap LDS reads
// with the MFMA cluster (LDS pipe ~2300cy/tile ~= MFMA 2480cy/tile; the R5
// double-barrier forced them to alternate -> 51% duty each).
// 16-row-band reads + 3-bit XOR swizzle = 0 bank conflicts (R3/R5 PMC);
// do NOT widen to 32-row bands (R4: 2.5e7 conflicts).
// ---------------------------------------------------------------------------

#define RD_A(BUF, MH)                                                         \
  { _Pragma("unroll") for (int mi = 0; mi < 4; ++mi) {                        \
      _Pragma("unroll") for (int k2 = 0; k2 < 2; ++k2) {                      \
        int lr = wr * 64 + mi * 16 + fr;                                      \
        aR[mi][k2] = *reinterpret_cast<const short8*>(                        \
            lds + (BUF) * 65536 + (MH) * 32768 + lr * 128 +                   \
            ((k2 * 64 + fkB) ^ ((lr & 7) << 4)));                             \
  } } }

#define RD_B(BUF, NH, DST)                                                    \
  { _Pragma("unroll") for (int ni = 0; ni < 2; ++ni) {                        \
      _Pragma("unroll") for (int k2 = 0; k2 < 2; ++k2) {                      \
        int lr = wc * 32 + ni * 16 + fr;                                      \
        DST[ni][k2] = *reinterpret_cast<const short8*>(                       \
            lds + (BUF) * 65536 + ((NH) ? 16384 : 49152) + lr * 128 +         \
            ((k2 * 64 + fkB) ^ ((lr & 7) << 4)));                             \
  } } }

#define PHASE(BUF, MH, NH, DO_A, DO_B0, DO_B1, VM)                            \
  {                                                                           \
    if (DO_A)  RD_A(BUF, MH)                                                  \
    if (DO_B0) RD_B(BUF, 0, bR0)                                              \
    if (DO_B1) RD_B(BUF, 1, bR1)                                              \
    issue_seq(seq); ++seq;                                                    \
    asm volatile("" ::: "memory");                                            \
    __builtin_amdgcn_s_barrier();                                             \
    asm volatile("" ::: "memory");                                            \
    __builtin_amdgcn_s_setprio(1);                                            \
    _Pragma("unroll") for (int mi = 0; mi < 4; ++mi)                          \
    _Pragma("unroll") for (int ni = 0; ni < 2; ++ni)                          \
    _Pragma("unroll") for (int k2 = 0; k2 < 2; ++k2)                          \
      acc[(MH) * 4 + mi][(NH) * 2 + ni] =                                     \
          __builtin_amdgcn_mfma_f32_16x16x32_bf16(                            \
              aR[mi][k2], (NH) ? bR1[ni][k2] : bR0[ni][k2],                   \
              acc[(MH) * 4 + mi][(NH) * 2 + ni], 0, 0, 0);                    \
    __builtin_amdgcn_s_setprio(0);                                            \
    if (VM) asm volatile("s_waitcnt vmcnt(6)" ::: "memory");                  \
  }

__global__ __launch_bounds__(512, 2) void gemm8p(
    const unsigned short* __restrict__ Abf,   // [T_DIM][K_DIM] bf16
    const unsigned short* __restrict__ Bbf,   // [M_DIM][K_DIM] bf16
    float* __restrict__ Y) {                  // [T_DIM][M_DIM]
    __shared__ __align__(16) unsigned char lds[131072];

    const int tid  = threadIdx.x;
    const int lane = tid & 63;
    const int wid  = tid >> 6;   // 0..7
    const int wr   = wid >> 2;   // 0..1 (M half of tile)
    const int wc   = wid & 3;    // 0..3 (N quarter of tile)

    // T1: bijective XCD swizzle (512 % 8 == 0)
    const int bid  = blockIdx.x;
    const int swz  = (bid & 7) * 64 + (bid >> 3);
    const int brow = swz >> 4;          // T/256 = 32
    const int bcol = swz & 15;          // M/256 = 16
    const int row0 = brow * 256;
    const int col0 = bcol * 256;

    const int fr  = lane & 15;
    const int fkB = (lane >> 4) * 16;   // byte offset of k-fragment

    f32x4 acc[8][4] = {};
    short8 aR[4][2];
    short8 bR0[2][2], bR1[2][2];

    // staging: seq s -> K-tile s>>2, region s&3 (stage order r0,r1,r2,r3)
    auto issue_seq = [&](int s) {
        int t   = s >> 2;
        int idx = s & 3;
        int buf = t & 1;
        int tc  = t < 64 ? t : 63;          // clamp tail prefetch (dead data)
        unsigned regoff = buf * 65536u + idx * 16384u;
        #pragma unroll
        for (int j = 0; j < 2; ++j) {
            int lr = j * 64 + wid * 8 + (lane >> 3);   // region row 0..127
            const unsigned short* Mat;
            int grow;
            if (idx == 0)      { Mat = Abf; grow = row0 + ((lr >> 6) << 7) + (lr & 63); }
            else if (idx == 2) { Mat = Abf; grow = row0 + 64 + ((lr >> 6) << 7) + (lr & 63); }
            else if (idx == 1) { Mat = Bbf; grow = col0 + ((lr >> 5) << 6) + 32 + (lr & 31); }
            else               { Mat = Bbf; grow = col0 + ((lr >> 5) << 6) + (lr & 31); }
            int cb = ((lane & 7) * 16) ^ ((lr & 7) << 4);   // T2 pre-swizzled source
            const char* g = (const char*)(Mat + (size_t)grow * K_DIM + tc * 64) + cb;
            async_copy16(g, lds + regoff + j * 8192u + wid * 1024u);  // linear dest
        }
    };

    // prologue: tile0 (4 regions), vmcnt(4), tile1 regions 0-2, vmcnt(6)
    int seq = 0;
    issue_seq(seq); ++seq;
    issue_seq(seq); ++seq;
    issue_seq(seq); ++seq;
    issue_seq(seq); ++seq;
    asm volatile("s_waitcnt vmcnt(4)" ::: "memory");
    issue_seq(seq); ++seq;
    issue_seq(seq); ++seq;
    issue_seq(seq); ++seq;
    asm volatile("s_waitcnt vmcnt(6)" ::: "memory");   // tile0 fully landed
    __builtin_amdgcn_s_barrier();
    asm volatile("" ::: "memory");

    // main loop: 32 iterations x 2 K-tiles, 4 phases each (snake quad order)
    for (int i = 0; i < 32; ++i) {
        PHASE(0, 0, 0, 1, 1, 0, 0)   // quad (0,0): A-MH0(8) + B-NH0(4)
        PHASE(0, 0, 1, 0, 0, 1, 0)   // quad (0,1): B-NH1(4), reuse aR
        PHASE(0, 1, 1, 1, 0, 0, 0)   // quad (1,1): A-MH1(8), reuse bR1
        PHASE(0, 1, 0, 0, 0, 0, 1)   // quad (1,0): reuse aR+bR0, vmcnt(6)
        PHASE(1, 0, 0, 1, 1, 0, 0)
        PHASE(1, 0, 1, 0, 0, 1, 0)
        PHASE(1, 1, 1, 1, 0, 0, 0)
        PHASE(1, 1, 0, 0, 0, 0, 1)
    }
    asm volatile("s_waitcnt vmcnt(0)" ::: "memory");   // epilogue drain

    // epilogue: C/D layout col=lane&15, row=(lane>>4)*4+reg
    const int rb = (lane >> 4) * 4;
    #pragma unroll
    for (int m = 0; m < 8; ++m)
        #pragma unroll
        for (int n = 0; n < 4; ++n)
            #pragma unroll
            for (int r = 0; r < 4; ++r)
                Y[(size_t)(row0 + wr * 128 + m * 16 + rb + r) * M_DIM +
                  col0 + wc * 64 + n * 16 + fr] = acc[m][n][r];
}

// ---------------------------------------------------------------------------
// Fallback m97-style GEMM (only if ws_size too small for bf16 staging)
// ---------------------------------------------------------------------------
template <bool BF32>
__global__ __launch_bounds__(256) void gemm_kernel(const float* __restrict__ Ap,
                                                   const void* __restrict__ Bp,
                                                   float* __restrict__ Y) {
    constexpr int BK = 64;
    __shared__ unsigned short lA[128 * BK];
    __shared__ unsigned short lB[128 * BK];

    const int tid  = threadIdx.x;
    const int lane = tid & 63;
    const int wid  = tid >> 6;
    const int wr   = wid >> 1;
    const int wc   = wid & 1;
    const int brow = blockIdx.x >> 5;
    const int bcol = blockIdx.x & 31;
    const int row0 = brow * 128;
    const int col0 = bcol * 128;

    f32x4 acc[4][4] = {};

    const int fr = lane & 15;
    const int fk = (lane >> 4) * 8;
    const int srow = lane >> 3;
    const int scol = (lane & 7) * 8;

    for (int k0 = 0; k0 < K_DIM; k0 += BK) {
        #pragma unroll
        for (int i = 0; i < 4; ++i) {
            const int c = wid * 4 + i;
            const int r = c * 8 + srow;
            const float* g = Ap + (size_t)(row0 + r) * K_DIM + k0 + scol;
            float4 v0 = *reinterpret_cast<const float4*>(g);
            float4 v1 = *reinterpret_cast<const float4*>(g + 4);
            short8 pk;
            pk[0] = (short)f2b(v0.x); pk[1] = (short)f2b(v0.y);
            pk[2] = (short)f2b(v0.z); pk[3] = (short)f2b(v0.w);
            pk[4] = (short)f2b(v1.x); pk[5] = (short)f2b(v1.y);
            pk[6] = (short)f2b(v1.z); pk[7] = (short)f2b(v1.w);
            *reinterpret_cast<short8*>(lA + c * 512 + lane * 8) = pk;
        }
        #pragma unroll
        for (int i = 0; i < 4; ++i) {
            const int c = wid * 4 + i;
            const int r = c * 8 + srow;
            if constexpr (!BF32) {
                async_copy16((const unsigned short*)Bp + (size_t)(col0 + r) * K_DIM + k0 + scol,
                             lB + c * 512);
            } else {
                const float* g = (const float*)Bp + (size_t)(col0 + r) * K_DIM + k0 + scol;
                float4 v0 = *reinterpret_cast<const float4*>(g);
                float4 v1 = *reinterpret_cast<const float4*>(g + 4);
                short8 pk;
                pk[0] = (short)f2b(v0.x); pk[1] = (short)f2b(v0.y);
                pk[2] = (short)f2b(v0.z); pk[3] = (short)f2b(v0.w);
                pk[4] = (short)f2b(v1.x); pk[5] = (short)f2b(v1.y);
                pk[6] = (short)f2b(v1.z); pk[7] = (short)f2b(v1.w);
                *reinterpret_cast<short8*>(lB + c * 512 + lane * 8) = pk;
            }
        }
        __syncthreads();

        #pragma unroll
        for (int kk = 0; kk < BK; kk += 32) {
            short8 af[4], bfr[4];
            #pragma unroll
            for (int m = 0; m < 4; ++m)
                af[m] = *reinterpret_cast<const short8*>(
                    lA + (wr * 64 + m * 16 + fr) * BK + kk + fk);
            #pragma unroll
            for (int n = 0; n < 4; ++n)
                bfr[n] = *reinterpret_cast<const short8*>(
                    lB + (wc * 64 + n * 16 + fr) * BK + kk + fk);
            #pragma unroll
            for (int m = 0; m < 4; ++m)
                #pragma unroll
                for (int n = 0; n < 4; ++n)
                    acc[m][n] = __builtin_amdgcn_mfma_f32_16x16x32_bf16(
                        af[m], bfr[n], acc[m][n], 0, 0, 0);
        }
        __syncthreads();
    }

    const int orow  = row0 + wr * 64;
    const int ocol  = col0 + wc * 64 + fr;
    const int rbase = (lane >> 4) * 4;
    #pragma unroll
    for (int m = 0; m < 4; ++m)
        #pragma unroll
        for (int n = 0; n < 4; ++n)
            #pragma unroll
            for (int r = 0; r < 4; ++r)
                Y[(size_t)(orow + m * 16 + rbase + r) * M_DIM + ocol + n * 16] =
                    acc[m][n][r];
}

// ---------------------------------------------------------------------------
extern "C" void kernel_launch(void* const* d_in, const int* in_sizes, int n_in,
                              void* d_out, int out_size, void* d_ws, size_t ws_size,
                              hipStream_t stream) {
    const float* x   = (const float*)d_in[0];
    const float* w   = (const float*)d_in[1];
    const float* mv  = (const float*)d_in[2];
    const float* lut = (const float*)d_in[3];

    float* y  = (float*)d_out;
    float* qw = y + (size_t)T_DIM * M_DIM;

    const size_t nx = (size_t)T_DIM * K_DIM;
    const size_t nw = (size_t)M_DIM * K_DIM;

    unsigned short* wsu = (unsigned short*)d_ws;
    const bool full  = ws_size >= (nx + nw) * sizeof(unsigned short);   // 96 MB
    const bool bonly = !full && ws_size >= nw * sizeof(unsigned short); // 32 MB

    unsigned short* xb  = full ? wsu : nullptr;
    unsigned short* qwb = full ? (wsu + nx) : (bonly ? wsu : nullptr);

    unsigned prep_blocks = (unsigned)(nw / 2048) + (full ? (unsigned)(nx / 2048) : 0u);
    prep_kernel<<<dim3(prep_blocks), dim3(256), 0, stream>>>(
        w, mv, lut, qw, qwb, x, xb);

    if (full) {
        dim3 grid((T_DIM / 256) * (M_DIM / 256));   // 32*16 = 512
        gemm8p<<<grid, dim3(512), 0, stream>>>(xb, qwb, y);
    } else {
        dim3 grid((T_DIM / 128) * (M_DIM / 128));   // 2048
        dim3 blk(256);
        if (bonly)
            gemm_kernel<false><<<grid, blk, 0, stream>>>(x, qwb, y);
        else
            gemm_kernel<true><<<grid, blk, 0, stream>>>(x, qw, y);
    }
}